// Round 17
// baseline (210.018 us; speedup 1.0000x reference)
//
#include <hip/hip_runtime.h>

#define NSEQ 2048
#define SCALE 0.04419417382415922f
#define LOG2E 1.44269504088896f

typedef __attribute__((ext_vector_type(8))) short short8v;
typedef __attribute__((ext_vector_type(4))) float f32x4;

#define GLOAD_LDS16(g, l) __builtin_amdgcn_global_load_lds( \
    (const __attribute__((address_space(1))) void*)(g),     \
    (__attribute__((address_space(3))) void*)(l), 16, 0, 0)

__device__ __forceinline__ unsigned short f2bf(float f) {
    unsigned int u = __builtin_bit_cast(unsigned int, f);
    u += 0x7fff + ((u >> 16) & 1);
    return (unsigned short)(u >> 16);
}

__device__ __forceinline__ float exp2_fast(float x) {
    float r; asm("v_exp_f32 %0, %1" : "=v"(r) : "v"(x)); return r;
}

// pack(bf16_round(a) lo, bf16_round(b) hi) : 2 adds + 1 v_perm_b32
__device__ __forceinline__ unsigned int pack_bf16_rh(float a, float b) {
    unsigned int ua = __builtin_bit_cast(unsigned int, a) + 0x8000u;
    unsigned int ub = __builtin_bit_cast(unsigned int, b) + 0x8000u;
    return __builtin_amdgcn_perm(ub, ua, 0x07060302u);
}

// ---------------- fp32 -> bf16 convert ----------------
__global__ __launch_bounds__(256) void cvt_bf16(const float* __restrict__ in,
                                                unsigned short* __restrict__ out, int n4) {
    int i = blockIdx.x * 256 + threadIdx.x;
    if (i < n4) {
        float4 v = ((const float4*)in)[i];
        ushort4 o;
        o.x = f2bf(v.x); o.y = f2bf(v.y); o.z = f2bf(v.z); o.w = f2bf(v.w);
        ((ushort4*)out)[i] = o;
    }
}

// ---------------- bf16 GEMM, BK=64, global_load_lds staging (R12, kept) ------
template<int MODE>
__global__ __launch_bounds__(256) void gemm_bf16(
    const unsigned short* __restrict__ A,
    const unsigned short* __restrict__ W,
    const float* __restrict__ bias,
    unsigned short* __restrict__ Qws,
    unsigned short* __restrict__ Kws,
    unsigned short* __restrict__ Vtws,
    float* __restrict__ Cout)
{
    __shared__ __attribute__((aligned(16))) unsigned short As[128 * 64];
    __shared__ __attribute__((aligned(16))) unsigned short Bs[128 * 64];

    int tid = threadIdx.x;
    int lane = tid & 63, w = tid >> 6;
    int wm = w >> 1, wn = w & 1;
    int g = lane >> 4, fr = lane & 15;
    int m0 = blockIdx.y * 128, n0 = blockIdx.x * 128;

    f32x4 acc[4][4] = {};

    for (int k0 = 0; k0 < 512; k0 += 64) {
        __syncthreads();
#pragma unroll
        for (int c = 0; c < 4; ++c) {
            int chunk = tid + c * 256;
            int row = chunk >> 3, c8 = chunk & 7;
            int gcol = (c8 ^ (row & 7)) * 8;
            GLOAD_LDS16(A + (size_t)(m0 + row) * 512 + k0 + gcol, &As[chunk * 8]);
            GLOAD_LDS16(W + (size_t)(n0 + row) * 512 + k0 + gcol, &Bs[chunk * 8]);
        }
        __syncthreads();
#pragma unroll
        for (int kk = 0; kk < 2; ++kk) {
            short8v af[4], bf[4];
#pragma unroll
            for (int mi = 0; mi < 4; ++mi) {
                int row = wm * 64 + mi * 16 + fr;
                af[mi] = *(const short8v*)(&As[row * 64 + (((kk * 4 + g) ^ (row & 7)) * 8)]);
            }
#pragma unroll
            for (int ni = 0; ni < 4; ++ni) {
                int row = wn * 64 + ni * 16 + fr;
                bf[ni] = *(const short8v*)(&Bs[row * 64 + (((kk * 4 + g) ^ (row & 7)) * 8)]);
            }
#pragma unroll
            for (int mi = 0; mi < 4; ++mi)
#pragma unroll
                for (int ni = 0; ni < 4; ++ni)
                    acc[mi][ni] = __builtin_amdgcn_mfma_f32_16x16x32_bf16(
                        af[mi], bf[ni], acc[mi][ni], 0, 0, 0);
        }
    }

#pragma unroll
    for (int mi = 0; mi < 4; ++mi) {
#pragma unroll
        for (int ni = 0; ni < 4; ++ni) {
            int col = n0 + wn * 64 + ni * 16 + fr;
            float bb = bias[col];
#pragma unroll
            for (int r = 0; r < 4; ++r) {
                int row = m0 + wm * 64 + mi * 16 + g * 4 + r;
                float val = acc[mi][ni][r] + bb;
                if (MODE == 0) {
                    int b = row >> 11, s = row & 2047;
                    if (col < 512) {
                        int h = col >> 6, d = col & 63;
                        Qws[(((size_t)(b * 8 + h) * NSEQ + s) << 6) + d] = f2bf(val * (SCALE * LOG2E));
                    } else if (col < 1024) {
                        int c2 = col - 512; int h = c2 >> 6, d = c2 & 63;
                        Kws[(((size_t)(b * 8 + h) * NSEQ + s) << 6) + d] = f2bf(val);
                    } else {
                        int c2 = col - 1024; int h = c2 >> 6, d = c2 & 63;
                        Vtws[((size_t)(b * 8 + h) * 64 + d) * NSEQ + s] = f2bf(val);
                    }
                } else {
                    Cout[(size_t)row * 512 + col] = val;
                }
            }
        }
    }
}

// ---------------- fused attention (R12 base + V direct-from-global) ----------
// Block = 512 thr = 8 waves, one (b,h); wave w owns 16 q-rows.
// LDS now holds only K (dbuf, swizzled keyed (row>>2)&7) + P relay = 32KB.
// V fragments are read straight from global Vt (L2/L3-resident, XCD-pinned):
// moves 96 of 264 LDS-cycles/wave-iter onto the near-idle TA/L1 pipe.
// vf loads issued right after QK so latency hides under exp+P-relay.
// Fixed-max softmax: P = exp2(S + g2*A_phi). Q pre-scaled by SCALE*LOG2E.
__global__ __launch_bounds__(512, 2) void attn_kernel(
    const unsigned short* __restrict__ Qws,
    const unsigned short* __restrict__ Kws,
    const unsigned short* __restrict__ Vtws,
    const float* __restrict__ A_phi,
    const float* __restrict__ gamma_p,
    unsigned short* __restrict__ Oout)
{
    __shared__ __attribute__((aligned(16))) unsigned short Ks[2][64 * 64];
    __shared__ __attribute__((aligned(16))) unsigned short Pl[8][16 * 64];

    int tid = threadIdx.x, lane = tid & 63, w = tid >> 6;
    int g = lane >> 4, fr = lane & 15;

    // swizzle: id%8 = XCD -> pin batch b to an XCD pair (A_phi/KV L2 reuse)
    int id = blockIdx.x;                 // 0..511
    int b = (id & 7) >> 1, p = id & 1;
    int j = id >> 3;                     // 0..63
    int h = j & 7;
    int qt = ((j >> 3) << 1) | p;        // 0..15
    int bh = b * 8 + h;
    int q0 = qt * 128 + w * 16;          // wave's q base
    float g2 = gamma_p[0] * LOG2E;

    const unsigned short* Kb = Kws + (size_t)bh * NSEQ * 64;
    const unsigned short* Vb = Vtws + (size_t)bh * 64 * NSEQ;
    const float* Ap = A_phi + (size_t)b * NSEQ * NSEQ;

    // Q fragments
    short8v qf[2];
#pragma unroll
    for (int dc = 0; dc < 2; ++dc)
        qf[dc] = *(const short8v*)(Qws + ((size_t)bh * NSEQ + q0 + fr) * 64 + dc * 32 + g * 8);

    // K staging: thread -> one 16B chunk
    int c = tid;
    int krow = c >> 3;                            // key 0..63
    int kchunk = c & 7;
    int swK = (kchunk ^ ((krow >> 2) & 7)) * 8;   // K: bank-group = f(row>>2)

    // per-lane V base: row d = nf*16+fr, key offset kc*32 + g*8
    const unsigned short* Vlane = Vb + (size_t)fr * NSEQ + g * 8;

    float l_lane[4] = {};
    f32x4 o_acc[4] = {};

    // prologue: stage K tile 0
    {
        short8v k0v = *(const short8v*)(Kb + c * 8);
        *(short8v*)(&Ks[0][krow * 64 + swK]) = k0v;
    }
    __syncthreads();

    for (int kt = 0; kt < NSEQ / 64; ++kt) {
        int cur = kt & 1;

        // T14: issue next K tile load early (held in regs)
        short8v kreg;
        if (kt < NSEQ / 64 - 1)
            kreg = *(const short8v*)(Kb + (kt + 1) * 4096 + c * 8);

        // A_phi tile (coalesced float4; lane's 4 consecutive keys 4*fr..4*fr+3)
        float4 av[4];
#pragma unroll
        for (int r = 0; r < 4; ++r)
            av[r] = *(const float4*)(Ap + (size_t)(q0 + g * 4 + r) * NSEQ + kt * 64 + 4 * fr);

        // S = QK^T, permuted key order: chunk kf col fr = key 4*fr+kf
        f32x4 sa[4] = {};
        __builtin_amdgcn_s_setprio(1);
#pragma unroll
        for (int kf = 0; kf < 4; ++kf) {
            int row = 4 * fr + kf;
#pragma unroll
            for (int dc = 0; dc < 2; ++dc) {
                short8v kfrag = *(const short8v*)(
                    &Ks[cur][row * 64 + (((dc * 4 + g) ^ ((row >> 2) & 7)) * 8)]);
                sa[kf] = __builtin_amdgcn_mfma_f32_16x16x32_bf16(qf[dc], kfrag, sa[kf], 0, 0, 0);
            }
        }
        __builtin_amdgcn_s_setprio(0);

        // issue V-fragment global loads NOW (latency hides under exp+relay)
        short8v vf[2][4];
#pragma unroll
        for (int kc = 0; kc < 2; ++kc)
#pragma unroll
            for (int nf = 0; nf < 4; ++nf)
                vf[kc][nf] = *(const short8v*)(
                    Vlane + (size_t)(nf * 16) * NSEQ + kt * 64 + kc * 32);

        // P = exp2(S + g2*A); per-lane l; relay to per-wave LDS (swizzled)
#pragma unroll
        for (int r = 0; r < 4; ++r) {
            float e0 = exp2_fast(fmaf(g2, av[r].x, sa[0][r]));
            float e1 = exp2_fast(fmaf(g2, av[r].y, sa[1][r]));
            float e2 = exp2_fast(fmaf(g2, av[r].z, sa[2][r]));
            float e3 = exp2_fast(fmaf(g2, av[r].w, sa[3][r]));
            l_lane[r] += (e0 + e1) + (e2 + e3);
            int rp = g * 4 + r;
            uint2 pp;
            pp.x = pack_bf16_rh(e0, e1);
            pp.y = pack_bf16_rh(e2, e3);
            *(uint2*)(&Pl[w][rp * 64 + (((fr >> 1) ^ (rp & 7)) * 8) + (fr & 1) * 4]) = pp;
        }
        asm volatile("s_waitcnt lgkmcnt(0)" ::: "memory");

        // O += P * V  (V operand from registers, loaded off the LDS pipe)
#pragma unroll
        for (int kc = 0; kc < 2; ++kc) {
            short8v pf = *(const short8v*)(
                &Pl[w][fr * 64 + (((kc * 4 + g) ^ (fr & 7)) * 8)]);
            __builtin_amdgcn_s_setprio(1);
#pragma unroll
            for (int nf = 0; nf < 4; ++nf)
                o_acc[nf] = __builtin_amdgcn_mfma_f32_16x16x32_bf16(
                    pf, vf[kc][nf], o_acc[nf], 0, 0, 0);
            __builtin_amdgcn_s_setprio(0);
        }

        // write staged K regs into the other buffer, then block-wide barrier
        if (kt < NSEQ / 64 - 1)
            *(short8v*)(&Ks[cur ^ 1][krow * 64 + swK]) = kreg;
        __syncthreads();
    }

    // epilogue: reduce l across 16-lane group, normalize, store bf16
#pragma unroll
    for (int r = 0; r < 4; ++r) {
        float l = l_lane[r];
        l += __shfl_xor(l, 1);
        l += __shfl_xor(l, 2);
        l += __shfl_xor(l, 4);
        l += __shfl_xor(l, 8);
        float inv = 1.0f / l;
        int qg = q0 + g * 4 + r;
#pragma unroll
        for (int nf = 0; nf < 4; ++nf)
            Oout[((size_t)b * NSEQ + qg) * 512 + h * 64 + nf * 16 + fr] =
                f2bf(o_acc[nf][r] * inv);
    }
}

extern "C" void kernel_launch(void* const* d_in, const int* in_sizes, int n_in,
                              void* d_out, int out_size, void* d_ws, size_t ws_size,
                              hipStream_t stream) {
    const float* x      = (const float*)d_in[0];
    const float* A_phi  = (const float*)d_in[1];
    const float* w_qkv  = (const float*)d_in[2];
    const float* b_qkv  = (const float*)d_in[3];
    const float* w_out  = (const float*)d_in[4];
    const float* b_out  = (const float*)d_in[5];
    const float* gamma  = (const float*)d_in[6];
    float* out = (float*)d_out;

    unsigned short* xb   = (unsigned short*)d_ws;
    unsigned short* wqb  = xb  + (size_t)8192 * 512;
    unsigned short* wob  = wqb + (size_t)1536 * 512;
    unsigned short* Qws  = wob + (size_t)512 * 512;
    unsigned short* Kws  = Qws + (size_t)4 * 8 * NSEQ * 64;
    unsigned short* Vtws = Kws + (size_t)4 * 8 * NSEQ * 64;
    unsigned short* Oat  = Vtws + (size_t)4 * 8 * NSEQ * 64;

    cvt_bf16<<<dim3(4096), dim3(256), 0, stream>>>(x, xb, 8192 * 512 / 4);
    cvt_bf16<<<dim3(768),  dim3(256), 0, stream>>>(w_qkv, wqb, 1536 * 512 / 4);
    cvt_bf16<<<dim3(256),  dim3(256), 0, stream>>>(w_out, wob, 512 * 512 / 4);

    gemm_bf16<0><<<dim3(12, 64), dim3(256), 0, stream>>>(
        xb, wqb, b_qkv, Qws, Kws, Vtws, nullptr);

    attn_kernel<<<dim3(512), dim3(512), 0, stream>>>(
        Qws, Kws, Vtws, A_phi, gamma, Oat);

    gemm_bf16<1><<<dim3(4, 64), dim3(256), 0, stream>>>(
        Oat, wob, b_out, nullptr, nullptr, nullptr, out);
}

// Round 18
// 124.277 us; speedup vs baseline: 1.6899x; 1.6899x over previous
//
#include <hip/hip_runtime.h>

#define NSEQ 2048
#define SCALE 0.04419417382415922f
#define LOG2E 1.44269504088896f

typedef __attribute__((ext_vector_type(8))) short short8v;
typedef __attribute__((ext_vector_type(4))) float f32x4;

#define GLOAD_LDS16(g, l) __builtin_amdgcn_global_load_lds( \
    (const __attribute__((address_space(1))) void*)(g),     \
    (__attribute__((address_space(3))) void*)(l), 16, 0, 0)

__device__ __forceinline__ unsigned short f2bf(float f) {
    unsigned int u = __builtin_bit_cast(unsigned int, f);
    u += 0x7fff + ((u >> 16) & 1);
    return (unsigned short)(u >> 16);
}

__device__ __forceinline__ float exp2_fast(float x) {
    float r; asm("v_exp_f32 %0, %1" : "=v"(r) : "v"(x)); return r;
}

// pack(bf16_round(a) lo, bf16_round(b) hi) : 2 adds + 1 v_perm_b32
__device__ __forceinline__ unsigned int pack_bf16_rh(float a, float b) {
    unsigned int ua = __builtin_bit_cast(unsigned int, a) + 0x8000u;
    unsigned int ub = __builtin_bit_cast(unsigned int, b) + 0x8000u;
    return __builtin_amdgcn_perm(ub, ua, 0x07060302u);
}

// ---------------- fp32 -> bf16 convert ----------------
__global__ __launch_bounds__(256) void cvt_bf16(const float* __restrict__ in,
                                                unsigned short* __restrict__ out, int n4) {
    int i = blockIdx.x * 256 + threadIdx.x;
    if (i < n4) {
        float4 v = ((const float4*)in)[i];
        ushort4 o;
        o.x = f2bf(v.x); o.y = f2bf(v.y); o.z = f2bf(v.z); o.w = f2bf(v.w);
        ((ushort4*)out)[i] = o;
    }
}

// ---------------- bf16 GEMM, BK=64, global_load_lds staging ----------
template<int MODE>
__global__ __launch_bounds__(256) void gemm_bf16(
    const unsigned short* __restrict__ A,
    const unsigned short* __restrict__ W,
    const float* __restrict__ bias,
    unsigned short* __restrict__ Qws,
    unsigned short* __restrict__ Kws,
    unsigned short* __restrict__ Vtws,
    float* __restrict__ Cout)
{
    __shared__ __attribute__((aligned(16))) unsigned short As[128 * 64];
    __shared__ __attribute__((aligned(16))) unsigned short Bs[128 * 64];

    int tid = threadIdx.x;
    int lane = tid & 63, w = tid >> 6;
    int wm = w >> 1, wn = w & 1;
    int g = lane >> 4, fr = lane & 15;
    int m0 = blockIdx.y * 128, n0 = blockIdx.x * 128;

    f32x4 acc[4][4] = {};

    for (int k0 = 0; k0 < 512; k0 += 64) {
        __syncthreads();
#pragma unroll
        for (int c = 0; c < 4; ++c) {
            int chunk = tid + c * 256;
            int row = chunk >> 3, c8 = chunk & 7;
            int gcol = (c8 ^ (row & 7)) * 8;
            GLOAD_LDS16(A + (size_t)(m0 + row) * 512 + k0 + gcol, &As[chunk * 8]);
            GLOAD_LDS16(W + (size_t)(n0 + row) * 512 + k0 + gcol, &Bs[chunk * 8]);
        }
        __syncthreads();
#pragma unroll
        for (int kk = 0; kk < 2; ++kk) {
            short8v af[4], bf[4];
#pragma unroll
            for (int mi = 0; mi < 4; ++mi) {
                int row = wm * 64 + mi * 16 + fr;
                af[mi] = *(const short8v*)(&As[row * 64 + (((kk * 4 + g) ^ (row & 7)) * 8)]);
            }
#pragma unroll
            for (int ni = 0; ni < 4; ++ni) {
                int row = wn * 64 + ni * 16 + fr;
                bf[ni] = *(const short8v*)(&Bs[row * 64 + (((kk * 4 + g) ^ (row & 7)) * 8)]);
            }
#pragma unroll
            for (int mi = 0; mi < 4; ++mi)
#pragma unroll
                for (int ni = 0; ni < 4; ++ni)
                    acc[mi][ni] = __builtin_amdgcn_mfma_f32_16x16x32_bf16(
                        af[mi], bf[ni], acc[mi][ni], 0, 0, 0);
        }
    }

#pragma unroll
    for (int mi = 0; mi < 4; ++mi) {
#pragma unroll
        for (int ni = 0; ni < 4; ++ni) {
            int col = n0 + wn * 64 + ni * 16 + fr;
            float bb = bias[col];
#pragma unroll
            for (int r = 0; r < 4; ++r) {
                int row = m0 + wm * 64 + mi * 16 + g * 4 + r;
                float val = acc[mi][ni][r] + bb;
                if (MODE == 0) {
                    int b = row >> 11, s = row & 2047;
                    if (col < 512) {
                        int h = col >> 6, d = col & 63;
                        Qws[(((size_t)(b * 8 + h) * NSEQ + s) << 6) + d] = f2bf(val * (SCALE * LOG2E));
                    } else if (col < 1024) {
                        int c2 = col - 512; int h = c2 >> 6, d = c2 & 63;
                        Kws[(((size_t)(b * 8 + h) * NSEQ + s) << 6) + d] = f2bf(val);
                    } else {
                        int c2 = col - 1024; int h = c2 >> 6, d = c2 & 63;
                        Vtws[((size_t)(b * 8 + h) * 64 + d) * NSEQ + s] = f2bf(val);
                    }
                } else {
                    Cout[(size_t)row * 512 + col] = val;
                }
            }
        }
    }
}

// ---------------- fused attention (R12 measured-best: attn 69.5us) ----------
// Block = 512 thr = 8 waves, one (b,h); wave w owns 16 q-rows.
// K/V tiles dbuf in XOR-swizzled LDS (48KB). K-frag reads touch rows 4*fr+kf
// (stride-4 rows = bank-aliased), so K's swizzle is keyed on (row>>2)&7;
// V reads adjacent rows (nf*16+fr) -> keyed (row&7). T14 reg-staged dbuf.
// Fixed-max softmax: P = exp2(S + g2*A_phi). Q pre-scaled by SCALE*LOG2E.
__global__ __launch_bounds__(512, 3) void attn_kernel(
    const unsigned short* __restrict__ Qws,
    const unsigned short* __restrict__ Kws,
    const unsigned short* __restrict__ Vtws,
    const float* __restrict__ A_phi,
    const float* __restrict__ gamma_p,
    unsigned short* __restrict__ Oout)
{
    __shared__ __attribute__((aligned(16))) unsigned short Ks[2][64 * 64];
    __shared__ __attribute__((aligned(16))) unsigned short Vts[2][64 * 64];
    __shared__ __attribute__((aligned(16))) unsigned short Pl[8][16 * 64];

    int tid = threadIdx.x, lane = tid & 63, w = tid >> 6;
    int g = lane >> 4, fr = lane & 15;

    // swizzle: id%8 = XCD -> pin batch b to an XCD pair (A_phi L2 reuse)
    int id = blockIdx.x;                 // 0..511
    int b = (id & 7) >> 1, p = id & 1;
    int j = id >> 3;                     // 0..63
    int h = j & 7;
    int qt = ((j >> 3) << 1) | p;        // 0..15
    int bh = b * 8 + h;
    int q0 = qt * 128 + w * 16;          // wave's q base
    float g2 = gamma_p[0] * LOG2E;

    const unsigned short* Kb = Kws + (size_t)bh * NSEQ * 64;
    const unsigned short* Vb = Vtws + (size_t)bh * 64 * NSEQ;
    const float* Ap = A_phi + (size_t)b * NSEQ * NSEQ;

    // Q fragments
    short8v qf[2];
#pragma unroll
    for (int dc = 0; dc < 2; ++dc)
        qf[dc] = *(const short8v*)(Qws + ((size_t)bh * NSEQ + q0 + fr) * 64 + dc * 32 + g * 8);

    // staging: thread -> one 16B K chunk + one 16B V chunk
    int c = tid;
    int krow = c >> 3;                            // K: key 0..63 ; V: d 0..63
    int kchunk = c & 7;
    int swK = (kchunk ^ ((krow >> 2) & 7)) * 8;   // K: bank-group = f(row>>2)
    int swV = (kchunk ^ (krow & 7)) * 8;          // V: adjacent-row pattern
    int kcol = kchunk * 8;

    float l_lane[4] = {};
    f32x4 o_acc[4] = {};

    // prologue: stage tile 0
    {
        short8v k0v = *(const short8v*)(Kb + c * 8);
        short8v v0v = *(const short8v*)(Vb + (size_t)krow * NSEQ + kcol);
        *(short8v*)(&Ks[0][krow * 64 + swK]) = k0v;
        *(short8v*)(&Vts[0][krow * 64 + swV]) = v0v;
    }
    __syncthreads();

    for (int kt = 0; kt < NSEQ / 64; ++kt) {
        int cur = kt & 1;

        // T14: issue next-tile global loads early
        short8v kreg, vreg;
        if (kt < NSEQ / 64 - 1) {
            kreg = *(const short8v*)(Kb + (kt + 1) * 4096 + c * 8);
            vreg = *(const short8v*)(Vb + (size_t)krow * NSEQ + (kt + 1) * 64 + kcol);
        }

        // A_phi tile (coalesced float4; lane's 4 consecutive keys 4*fr..4*fr+3)
        float4 av[4];
#pragma unroll
        for (int r = 0; r < 4; ++r)
            av[r] = *(const float4*)(Ap + (size_t)(q0 + g * 4 + r) * NSEQ + kt * 64 + 4 * fr);

        // S = QK^T, permuted key order: chunk kf col fr = key 4*fr+kf
        f32x4 sa[4] = {};
        __builtin_amdgcn_s_setprio(1);
#pragma unroll
        for (int kf = 0; kf < 4; ++kf) {
            int row = 4 * fr + kf;
#pragma unroll
            for (int dc = 0; dc < 2; ++dc) {
                short8v kfrag = *(const short8v*)(
                    &Ks[cur][row * 64 + (((dc * 4 + g) ^ ((row >> 2) & 7)) * 8)]);
                sa[kf] = __builtin_amdgcn_mfma_f32_16x16x32_bf16(qf[dc], kfrag, sa[kf], 0, 0, 0);
            }
        }
        __builtin_amdgcn_s_setprio(0);

        // P = exp2(S + g2*A); per-lane l; relay to per-wave LDS (swizzled)
#pragma unroll
        for (int r = 0; r < 4; ++r) {
            float e0 = exp2_fast(fmaf(g2, av[r].x, sa[0][r]));
            float e1 = exp2_fast(fmaf(g2, av[r].y, sa[1][r]));
            float e2 = exp2_fast(fmaf(g2, av[r].z, sa[2][r]));
            float e3 = exp2_fast(fmaf(g2, av[r].w, sa[3][r]));
            l_lane[r] += (e0 + e1) + (e2 + e3);
            int rp = g * 4 + r;
            uint2 pp;
            pp.x = pack_bf16_rh(e0, e1);
            pp.y = pack_bf16_rh(e2, e3);
            *(uint2*)(&Pl[w][rp * 64 + (((fr >> 1) ^ (rp & 7)) * 8) + (fr & 1) * 4]) = pp;
        }
        asm volatile("s_waitcnt lgkmcnt(0)" ::: "memory");

        // O += P * V
#pragma unroll
        for (int kc = 0; kc < 2; ++kc) {
            short8v pf = *(const short8v*)(
                &Pl[w][fr * 64 + (((kc * 4 + g) ^ (fr & 7)) * 8)]);
            __builtin_amdgcn_s_setprio(1);
#pragma unroll
            for (int nf = 0; nf < 4; ++nf) {
                int vrow = nf * 16 + fr;
                short8v vf = *(const short8v*)(
                    &Vts[cur][vrow * 64 + (((kc * 4 + g) ^ (vrow & 7)) * 8)]);
                o_acc[nf] = __builtin_amdgcn_mfma_f32_16x16x32_bf16(pf, vf, o_acc[nf], 0, 0, 0);
            }
            __builtin_amdgcn_s_setprio(0);
        }

        // write staged regs into the other buffer, then block-wide barrier
        if (kt < NSEQ / 64 - 1) {
            *(short8v*)(&Ks[cur ^ 1][krow * 64 + swK]) = kreg;
            *(short8v*)(&Vts[cur ^ 1][krow * 64 + swV]) = vreg;
        }
        __syncthreads();
    }

    // epilogue: reduce l across 16-lane group, normalize, store bf16
#pragma unroll
    for (int r = 0; r < 4; ++r) {
        float l = l_lane[r];
        l += __shfl_xor(l, 1);
        l += __shfl_xor(l, 2);
        l += __shfl_xor(l, 4);
        l += __shfl_xor(l, 8);
        float inv = 1.0f / l;
        int qg = q0 + g * 4 + r;
#pragma unroll
        for (int nf = 0; nf < 4; ++nf)
            Oout[((size_t)b * NSEQ + qg) * 512 + h * 64 + nf * 16 + fr] =
                f2bf(o_acc[nf][r] * inv);
    }
}

extern "C" void kernel_launch(void* const* d_in, const int* in_sizes, int n_in,
                              void* d_out, int out_size, void* d_ws, size_t ws_size,
                              hipStream_t stream) {
    const float* x      = (const float*)d_in[0];
    const float* A_phi  = (const float*)d_in[1];
    const float* w_qkv  = (const float*)d_in[2];
    const float* b_qkv  = (const float*)d_in[3];
    const float* w_out  = (const float*)d_in[4];
    const float* b_out  = (const float*)d_in[5];
    const float* gamma  = (const float*)d_in[6];
    float* out = (float*)d_out;

    unsigned short* xb   = (unsigned short*)d_ws;
    unsigned short* wqb  = xb  + (size_t)8192 * 512;
    unsigned short* wob  = wqb + (size_t)1536 * 512;
    unsigned short* Qws  = wob + (size_t)512 * 512;
    unsigned short* Kws  = Qws + (size_t)4 * 8 * NSEQ * 64;
    unsigned short* Vtws = Kws + (size_t)4 * 8 * NSEQ * 64;
    unsigned short* Oat  = Vtws + (size_t)4 * 8 * NSEQ * 64;

    cvt_bf16<<<dim3(4096), dim3(256), 0, stream>>>(x, xb, 8192 * 512 / 4);
    cvt_bf16<<<dim3(768),  dim3(256), 0, stream>>>(w_qkv, wqb, 1536 * 512 / 4);
    cvt_bf16<<<dim3(256),  dim3(256), 0, stream>>>(w_out, wob, 512 * 512 / 4);

    gemm_bf16<0><<<dim3(12, 64), dim3(256), 0, stream>>>(
        xb, wqb, b_qkv, Qws, Kws, Vtws, nullptr);

    attn_kernel<<<dim3(512), dim3(512), 0, stream>>>(
        Qws, Kws, Vtws, A_phi, gamma, Oat);

    gemm_bf16<1><<<dim3(4, 64), dim3(256), 0, stream>>>(
        Oat, wob, b_out, nullptr, nullptr, nullptr, out);
}

// Round 19
// 107.482 us; speedup vs baseline: 1.9540x; 1.1563x over previous
//
#include <hip/hip_runtime.h>

#define NSEQ 2048
#define SCALE 0.04419417382415922f
#define LOG2E 1.44269504088896f

typedef __attribute__((ext_vector_type(8))) short short8v;
typedef __attribute__((ext_vector_type(4))) float f32x4;

#define GLOAD_LDS16(g, l) __builtin_amdgcn_global_load_lds( \
    (const __attribute__((address_space(1))) void*)(g),     \
    (__attribute__((address_space(3))) void*)(l), 16, 0, 0)

__device__ __forceinline__ unsigned short f2bf(float f) {
    unsigned int u = __builtin_bit_cast(unsigned int, f);
    u += 0x7fff + ((u >> 16) & 1);
    return (unsigned short)(u >> 16);
}

__device__ __forceinline__ float exp2_fast(float x) {
    float r; asm("v_exp_f32 %0, %1" : "=v"(r) : "v"(x)); return r;
}

// pack(bf16_round(a) lo, bf16_round(b) hi) : 2 adds + 1 v_perm_b32
__device__ __forceinline__ unsigned int pack_bf16_rh(float a, float b) {
    unsigned int ua = __builtin_bit_cast(unsigned int, a) + 0x8000u;
    unsigned int ub = __builtin_bit_cast(unsigned int, b) + 0x8000u;
    return __builtin_amdgcn_perm(ub, ua, 0x07060302u);
}

// ---------------- fp32 -> bf16 convert, all three tensors in one launch ------
// blocks [0,4096): x (1048576 float4s); [4096,4864): w_qkv (196608);
// [4864,5120): w_out (65536). All exact multiples of 256 -> no bounds checks.
__global__ __launch_bounds__(256) void cvt_all(
    const float* __restrict__ x, const float* __restrict__ wq,
    const float* __restrict__ wo,
    unsigned short* __restrict__ xb, unsigned short* __restrict__ wqb,
    unsigned short* __restrict__ wob)
{
    int bid = blockIdx.x;
    const float* in;
    unsigned short* out;
    int i;
    if (bid < 4096)      { in = x;  out = xb;  i = bid * 256 + threadIdx.x; }
    else if (bid < 4864) { in = wq; out = wqb; i = (bid - 4096) * 256 + threadIdx.x; }
    else                 { in = wo; out = wob; i = (bid - 4864) * 256 + threadIdx.x; }
    float4 v = ((const float4*)in)[i];
    ushort4 o;
    o.x = f2bf(v.x); o.y = f2bf(v.y); o.z = f2bf(v.z); o.w = f2bf(v.w);
    ((ushort4*)out)[i] = o;
}

// ---------------- bf16 GEMM, BK=64, global_load_lds staging ------------------
// Tile BM x BN, 4 waves as 2x2, per-wave tile (BM/2)x(BN/2).
// MODE 0 (128x128): scatter to Q (scaled), K, V^T; V-writes packed b64.
// MODE 1 (64x128):  fp32 out + bias (grid 4x128 = 512 blocks -> 2 blocks/CU).
template<int MODE, int BM, int BN>
__global__ __launch_bounds__(256) void gemm_bf16(
    const unsigned short* __restrict__ A,
    const unsigned short* __restrict__ W,
    const float* __restrict__ bias,
    unsigned short* __restrict__ Qws,
    unsigned short* __restrict__ Kws,
    unsigned short* __restrict__ Vtws,
    float* __restrict__ Cout)
{
    const int WM = BM / 2, WN = BN / 2;
    __shared__ __attribute__((aligned(16))) unsigned short As[BM * 64];
    __shared__ __attribute__((aligned(16))) unsigned short Bs[BN * 64];

    int tid = threadIdx.x;
    int lane = tid & 63, w = tid >> 6;
    int wm = w >> 1, wn = w & 1;
    int g = lane >> 4, fr = lane & 15;
    int m0 = blockIdx.y * BM, n0 = blockIdx.x * BN;

    f32x4 acc[WM / 16][4] = {};

    for (int k0 = 0; k0 < 512; k0 += 64) {
        __syncthreads();
#pragma unroll
        for (int c = 0; c < BM * 8 / 256; ++c) {
            int chunk = tid + c * 256;
            int row = chunk >> 3, c8 = chunk & 7;
            int gcol = (c8 ^ (row & 7)) * 8;
            GLOAD_LDS16(A + (size_t)(m0 + row) * 512 + k0 + gcol, &As[chunk * 8]);
        }
#pragma unroll
        for (int c = 0; c < BN * 8 / 256; ++c) {
            int chunk = tid + c * 256;
            int row = chunk >> 3, c8 = chunk & 7;
            int gcol = (c8 ^ (row & 7)) * 8;
            GLOAD_LDS16(W + (size_t)(n0 + row) * 512 + k0 + gcol, &Bs[chunk * 8]);
        }
        __syncthreads();
#pragma unroll
        for (int kk = 0; kk < 2; ++kk) {
            short8v af[WM / 16], bf[4];
#pragma unroll
            for (int mi = 0; mi < WM / 16; ++mi) {
                int row = wm * WM + mi * 16 + fr;
                af[mi] = *(const short8v*)(&As[row * 64 + (((kk * 4 + g) ^ (row & 7)) * 8)]);
            }
#pragma unroll
            for (int ni = 0; ni < 4; ++ni) {
                int row = wn * WN + ni * 16 + fr;
                bf[ni] = *(const short8v*)(&Bs[row * 64 + (((kk * 4 + g) ^ (row & 7)) * 8)]);
            }
#pragma unroll
            for (int mi = 0; mi < WM / 16; ++mi)
#pragma unroll
                for (int ni = 0; ni < 4; ++ni)
                    acc[mi][ni] = __builtin_amdgcn_mfma_f32_16x16x32_bf16(
                        af[mi], bf[ni], acc[mi][ni], 0, 0, 0);
        }
    }

#pragma unroll
    for (int mi = 0; mi < WM / 16; ++mi) {
#pragma unroll
        for (int ni = 0; ni < 4; ++ni) {
            int col = n0 + wn * WN + ni * 16 + fr;
            float bb = bias[col];
            int row0 = m0 + wm * WM + mi * 16 + g * 4;
            if (MODE == 0) {
                int b = row0 >> 11, s0 = row0 & 2047;
                if (col < 512) {
                    int h = col >> 6, d = col & 63;
#pragma unroll
                    for (int r = 0; r < 4; ++r)
                        Qws[(((size_t)(b * 8 + h) * NSEQ + s0 + r) << 6) + d] =
                            f2bf((acc[mi][ni][r] + bb) * (SCALE * LOG2E));
                } else if (col < 1024) {
                    int c2 = col - 512; int h = c2 >> 6, d = c2 & 63;
#pragma unroll
                    for (int r = 0; r < 4; ++r)
                        Kws[(((size_t)(b * 8 + h) * NSEQ + s0 + r) << 6) + d] =
                            f2bf(acc[mi][ni][r] + bb);
                } else {
                    // V^T: s consecutive over r -> packed 8B store
                    int c2 = col - 1024; int h = c2 >> 6, d = c2 & 63;
                    uint2 pv;
                    pv.x = pack_bf16_rh(acc[mi][ni][0] + bb, acc[mi][ni][1] + bb);
                    pv.y = pack_bf16_rh(acc[mi][ni][2] + bb, acc[mi][ni][3] + bb);
                    *(uint2*)(&Vtws[((size_t)(b * 8 + h) * 64 + d) * NSEQ + s0]) = pv;
                }
            } else {
#pragma unroll
                for (int r = 0; r < 4; ++r)
                    Cout[(size_t)(row0 + r) * 512 + col] = acc[mi][ni][r] + bb;
            }
        }
    }
}

// ---------------- fused attention (R12 measured-best: attn ~70us) -----------
// Block = 512 thr = 8 waves, one (b,h); wave w owns 16 q-rows.
// K/V tiles dbuf in XOR-swizzled LDS (48KB). K-frag reads touch rows 4*fr+kf
// (stride-4 rows = bank-aliased), so K's swizzle is keyed on (row>>2)&7;
// V reads adjacent rows (nf*16+fr) -> keyed (row&7). T14 reg-staged dbuf.
// Fixed-max softmax: P = exp2(S + g2*A_phi). Q pre-scaled by SCALE*LOG2E.
__global__ __launch_bounds__(512, 3) void attn_kernel(
    const unsigned short* __restrict__ Qws,
    const unsigned short* __restrict__ Kws,
    const unsigned short* __restrict__ Vtws,
    const float* __restrict__ A_phi,
    const float* __restrict__ gamma_p,
    unsigned short* __restrict__ Oout)
{
    __shared__ __attribute__((aligned(16))) unsigned short Ks[2][64 * 64];
    __shared__ __attribute__((aligned(16))) unsigned short Vts[2][64 * 64];
    __shared__ __attribute__((aligned(16))) unsigned short Pl[8][16 * 64];

    int tid = threadIdx.x, lane = tid & 63, w = tid >> 6;
    int g = lane >> 4, fr = lane & 15;

    // swizzle: id%8 = XCD -> pin batch b to an XCD pair (A_phi L2 reuse)
    int id = blockIdx.x;                 // 0..511
    int b = (id & 7) >> 1, p = id & 1;
    int j = id >> 3;                     // 0..63
    int h = j & 7;
    int qt = ((j >> 3) << 1) | p;        // 0..15
    int bh = b * 8 + h;
    int q0 = qt * 128 + w * 16;          // wave's q base
    float g2 = gamma_p[0] * LOG2E;

    const unsigned short* Kb = Kws + (size_t)bh * NSEQ * 64;
    const unsigned short* Vb = Vtws + (size_t)bh * 64 * NSEQ;
    const float* Ap = A_phi + (size_t)b * NSEQ * NSEQ;

    // Q fragments
    short8v qf[2];
#pragma unroll
    for (int dc = 0; dc < 2; ++dc)
        qf[dc] = *(const short8v*)(Qws + ((size_t)bh * NSEQ + q0 + fr) * 64 + dc * 32 + g * 8);

    // staging: thread -> one 16B K chunk + one 16B V chunk
    int c = tid;
    int krow = c >> 3;                            // K: key 0..63 ; V: d 0..63
    int kchunk = c & 7;
    int swK = (kchunk ^ ((krow >> 2) & 7)) * 8;   // K: bank-group = f(row>>2)
    int swV = (kchunk ^ (krow & 7)) * 8;          // V: adjacent-row pattern
    int kcol = kchunk * 8;

    float l_lane[4] = {};
    f32x4 o_acc[4] = {};

    // prologue: stage tile 0
    {
        short8v k0v = *(const short8v*)(Kb + c * 8);
        short8v v0v = *(const short8v*)(Vb + (size_t)krow * NSEQ + kcol);
        *(short8v*)(&Ks[0][krow * 64 + swK]) = k0v;
        *(short8v*)(&Vts[0][krow * 64 + swV]) = v0v;
    }
    __syncthreads();

    for (int kt = 0; kt < NSEQ / 64; ++kt) {
        int cur = kt & 1;

        // T14: issue next-tile global loads early
        short8v kreg, vreg;
        if (kt < NSEQ / 64 - 1) {
            kreg = *(const short8v*)(Kb + (kt + 1) * 4096 + c * 8);
            vreg = *(const short8v*)(Vb + (size_t)krow * NSEQ + (kt + 1) * 64 + kcol);
        }

        // A_phi tile (coalesced float4; lane's 4 consecutive keys 4*fr..4*fr+3)
        float4 av[4];
#pragma unroll
        for (int r = 0; r < 4; ++r)
            av[r] = *(const float4*)(Ap + (size_t)(q0 + g * 4 + r) * NSEQ + kt * 64 + 4 * fr);

        // S = QK^T, permuted key order: chunk kf col fr = key 4*fr+kf
        f32x4 sa[4] = {};
        __builtin_amdgcn_s_setprio(1);
#pragma unroll
        for (int kf = 0; kf < 4; ++kf) {
            int row = 4 * fr + kf;
#pragma unroll
            for (int dc = 0; dc < 2; ++dc) {
                short8v kfrag = *(const short8v*)(
                    &Ks[cur][row * 64 + (((dc * 4 + g) ^ ((row >> 2) & 7)) * 8)]);
                sa[kf] = __builtin_amdgcn_mfma_f32_16x16x32_bf16(qf[dc], kfrag, sa[kf], 0, 0, 0);
            }
        }
        __builtin_amdgcn_s_setprio(0);

        // P = exp2(S + g2*A); per-lane l; relay to per-wave LDS (swizzled)
#pragma unroll
        for (int r = 0; r < 4; ++r) {
            float e0 = exp2_fast(fmaf(g2, av[r].x, sa[0][r]));
            float e1 = exp2_fast(fmaf(g2, av[r].y, sa[1][r]));
            float e2 = exp2_fast(fmaf(g2, av[r].z, sa[2][r]));
            float e3 = exp2_fast(fmaf(g2, av[r].w, sa[3][r]));
            l_lane[r] += (e0 + e1) + (e2 + e3);
            int rp = g * 4 + r;
            uint2 pp;
            pp.x = pack_bf16_rh(e0, e1);
            pp.y = pack_bf16_rh(e2, e3);
            *(uint2*)(&Pl[w][rp * 64 + (((fr >> 1) ^ (rp & 7)) * 8) + (fr & 1) * 4]) = pp;
        }
        asm volatile("s_waitcnt lgkmcnt(0)" ::: "memory");

        // O += P * V
#pragma unroll
        for (int kc = 0; kc < 2; ++kc) {
            short8v pf = *(const short8v*)(
                &Pl[w][fr * 64 + (((kc * 4 + g) ^ (fr & 7)) * 8)]);
            __builtin_amdgcn_s_setprio(1);
#pragma unroll
            for (int nf = 0; nf < 4; ++nf) {
                int vrow = nf * 16 + fr;
                short8v vf = *(const short8v*)(
                    &Vts[cur][vrow * 64 + (((kc * 4 + g) ^ (vrow & 7)) * 8)]);
                o_acc[nf] = __builtin_amdgcn_mfma_f32_16x16x32_bf16(pf, vf, o_acc[nf], 0, 0, 0);
            }
            __builtin_amdgcn_s_setprio(0);
        }

        // write staged regs into the other buffer, then block-wide barrier
        if (kt < NSEQ / 64 - 1) {
            *(short8v*)(&Ks[cur ^ 1][krow * 64 + swK]) = kreg;
            *(short8v*)(&Vts[cur ^ 1][krow * 64 + swV]) = vreg;
        }
        __syncthreads();
    }

    // epilogue: reduce l across 16-lane group, normalize, store bf16
#pragma unroll
    for (int r = 0; r < 4; ++r) {
        float l = l_lane[r];
        l += __shfl_xor(l, 1);
        l += __shfl_xor(l, 2);
        l += __shfl_xor(l, 4);
        l += __shfl_xor(l, 8);
        float inv = 1.0f / l;
        int qg = q0 + g * 4 + r;
#pragma unroll
        for (int nf = 0; nf < 4; ++nf)
            Oout[((size_t)b * NSEQ + qg) * 512 + h * 64 + nf * 16 + fr] =
                f2bf(o_acc[nf][r] * inv);
    }
}

extern "C" void kernel_launch(void* const* d_in, const int* in_sizes, int n_in,
                              void* d_out, int out_size, void* d_ws, size_t ws_size,
                              hipStream_t stream) {
    const float* x      = (const float*)d_in[0];
    const float* A_phi  = (const float*)d_in[1];
    const float* w_qkv  = (const float*)d_in[2];
    const float* b_qkv  = (const float*)d_in[3];
    const float* w_out  = (const float*)d_in[4];
    const float* b_out  = (const float*)d_in[5];
    const float* gamma  = (const float*)d_in[6];
    float* out = (float*)d_out;

    unsigned short* xb   = (unsigned short*)d_ws;
    unsigned short* wqb  = xb  + (size_t)8192 * 512;
    unsigned short* wob  = wqb + (size_t)1536 * 512;
    unsigned short* Qws  = wob + (size_t)512 * 512;
    unsigned short* Kws  = Qws + (size_t)4 * 8 * NSEQ * 64;
    unsigned short* Vtws = Kws + (size_t)4 * 8 * NSEQ * 64;
    unsigned short* Oat  = Vtws + (size_t)4 * 8 * NSEQ * 64;

    cvt_all<<<dim3(5120), dim3(256), 0, stream>>>(x, w_qkv, w_out, xb, wqb, wob);

    gemm_bf16<0, 128, 128><<<dim3(12, 64), dim3(256), 0, stream>>>(
        xb, wqb, b_qkv, Qws, Kws, Vtws, nullptr);

    attn_kernel<<<dim3(512), dim3(512), 0, stream>>>(
        Qws, Kws, Vtws, A_phi, gamma, Oat);

    gemm_bf16<1, 64, 128><<<dim3(4, 128), dim3(256), 0, stream>>>(
        Oat, wob, b_out, nullptr, nullptr, nullptr, out);
}

// Round 20
// 104.830 us; speedup vs baseline: 2.0034x; 1.0253x over previous
//
#include <hip/hip_runtime.h>

#define NSEQ 2048
#define SCALE 0.04419417382415922f
#define LOG2E 1.44269504088896f

typedef __attribute__((ext_vector_type(8))) short short8v;
typedef __attribute__((ext_vector_type(4))) float f32x4;

#define GLOAD_LDS16(g, l) __builtin_amdgcn_global_load_lds( \
    (const __attribute__((address_space(1))) void*)(g),     \
    (__attribute__((address_space(3))) void*)(l), 16, 0, 0)

__device__ __forceinline__ unsigned short f2bf(float f) {
    unsigned int u = __builtin_bit_cast(unsigned int, f);
    u += 0x7fff + ((u >> 16) & 1);
    return (unsigned short)(u >> 16);
}

__device__ __forceinline__ float exp2_fast(float x) {
    float r; asm("v_exp_f32 %0, %1" : "=v"(r) : "v"(x)); return r;
}

// pack(bf16_round(a) lo, bf16_round(b) hi) : 2 adds + 1 v_perm_b32
__device__ __forceinline__ unsigned int pack_bf16_rh(float a, float b) {
    unsigned int ua = __builtin_bit_cast(unsigned int, a) + 0x8000u;
    unsigned int ub = __builtin_bit_cast(unsigned int, b) + 0x8000u;
    return __builtin_amdgcn_perm(ub, ua, 0x07060302u);
}

// ---------------- fp32 -> bf16 convert, all three tensors in one launch ------
__global__ __launch_bounds__(256) void cvt_all(
    const float* __restrict__ x, const float* __restrict__ wq,
    const float* __restrict__ wo,
    unsigned short* __restrict__ xb, unsigned short* __restrict__ wqb,
    unsigned short* __restrict__ wob)
{
    int bid = blockIdx.x;
    const float* in;
    unsigned short* out;
    int i;
    if (bid < 4096)      { in = x;  out = xb;  i = bid * 256 + threadIdx.x; }
    else if (bid < 4864) { in = wq; out = wqb; i = (bid - 4096) * 256 + threadIdx.x; }
    else                 { in = wo; out = wob; i = (bid - 4864) * 256 + threadIdx.x; }
    float4 v = ((const float4*)in)[i];
    ushort4 o;
    o.x = f2bf(v.x); o.y = f2bf(v.y); o.z = f2bf(v.z); o.w = f2bf(v.w);
    ((ushort4*)out)[i] = o;
}

// ---------------- bf16 GEMM, BK=64, global_load_lds staging ------------------
// Tile BM x BN, 4 waves as 2x2. NX = grid width (compile-time for cheap div).
// XCD-aware swizzle: wgid=(id&7)*(nwg/8)+(id>>3) pins 8 consecutive m-rows
// per XCD -> A-panels + B stay L2-resident (T1; nwg%8==0 bijective).
// MODE 0 (128x128): scatter to Q (scaled), K, V^T; V-writes packed b64.
// MODE 1 (64x128):  fp32 out + bias.
template<int MODE, int BM, int BN, int NX, int NWG>
__global__ __launch_bounds__(256) void gemm_bf16(
    const unsigned short* __restrict__ A,
    const unsigned short* __restrict__ W,
    const float* __restrict__ bias,
    unsigned short* __restrict__ Qws,
    unsigned short* __restrict__ Kws,
    unsigned short* __restrict__ Vtws,
    float* __restrict__ Cout)
{
    const int WM = BM / 2, WN = BN / 2;
    __shared__ __attribute__((aligned(16))) unsigned short As[BM * 64];
    __shared__ __attribute__((aligned(16))) unsigned short Bs[BN * 64];

    int tid = threadIdx.x;
    int lane = tid & 63, w = tid >> 6;
    int wm = w >> 1, wn = w & 1;
    int g = lane >> 4, fr = lane & 15;

    int id = blockIdx.x + NX * blockIdx.y;
    int wgid = (id & 7) * (NWG / 8) + (id >> 3);
    int m0 = (wgid / NX) * BM, n0 = (wgid % NX) * BN;

    f32x4 acc[WM / 16][4] = {};

    for (int k0 = 0; k0 < 512; k0 += 64) {
        __syncthreads();
#pragma unroll
        for (int c = 0; c < BM * 8 / 256; ++c) {
            int chunk = tid + c * 256;
            int row = chunk >> 3, c8 = chunk & 7;
            int gcol = (c8 ^ (row & 7)) * 8;
            GLOAD_LDS16(A + (size_t)(m0 + row) * 512 + k0 + gcol, &As[chunk * 8]);
        }
#pragma unroll
        for (int c = 0; c < BN * 8 / 256; ++c) {
            int chunk = tid + c * 256;
            int row = chunk >> 3, c8 = chunk & 7;
            int gcol = (c8 ^ (row & 7)) * 8;
            GLOAD_LDS16(W + (size_t)(n0 + row) * 512 + k0 + gcol, &Bs[chunk * 8]);
        }
        __syncthreads();
#pragma unroll
        for (int kk = 0; kk < 2; ++kk) {
            short8v af[WM / 16], bf[4];
#pragma unroll
            for (int mi = 0; mi < WM / 16; ++mi) {
                int row = wm * WM + mi * 16 + fr;
                af[mi] = *(const short8v*)(&As[row * 64 + (((kk * 4 + g) ^ (row & 7)) * 8)]);
            }
#pragma unroll
            for (int ni = 0; ni < 4; ++ni) {
                int row = wn * WN + ni * 16 + fr;
                bf[ni] = *(const short8v*)(&Bs[row * 64 + (((kk * 4 + g) ^ (row & 7)) * 8)]);
            }
#pragma unroll
            for (int mi = 0; mi < WM / 16; ++mi)
#pragma unroll
                for (int ni = 0; ni < 4; ++ni)
                    acc[mi][ni] = __builtin_amdgcn_mfma_f32_16x16x32_bf16(
                        af[mi], bf[ni], acc[mi][ni], 0, 0, 0);
        }
    }

#pragma unroll
    for (int mi = 0; mi < WM / 16; ++mi) {
#pragma unroll
        for (int ni = 0; ni < 4; ++ni) {
            int col = n0 + wn * WN + ni * 16 + fr;
            float bb = bias[col];
            int row0 = m0 + wm * WM + mi * 16 + g * 4;
            if (MODE == 0) {
                int b = row0 >> 11, s0 = row0 & 2047;
                if (col < 512) {
                    int h = col >> 6, d = col & 63;
#pragma unroll
                    for (int r = 0; r < 4; ++r)
                        Qws[(((size_t)(b * 8 + h) * NSEQ + s0 + r) << 6) + d] =
                            f2bf((acc[mi][ni][r] + bb) * (SCALE * LOG2E));
                } else if (col < 1024) {
                    int c2 = col - 512; int h = c2 >> 6, d = c2 & 63;
#pragma unroll
                    for (int r = 0; r < 4; ++r)
                        Kws[(((size_t)(b * 8 + h) * NSEQ + s0 + r) << 6) + d] =
                            f2bf(acc[mi][ni][r] + bb);
                } else {
                    int c2 = col - 1024; int h = c2 >> 6, d = c2 & 63;
                    uint2 pv;
                    pv.x = pack_bf16_rh(acc[mi][ni][0] + bb, acc[mi][ni][1] + bb);
                    pv.y = pack_bf16_rh(acc[mi][ni][2] + bb, acc[mi][ni][3] + bb);
                    *(uint2*)(&Vtws[((size_t)(b * 8 + h) * 64 + d) * NSEQ + s0]) = pv;
                }
            } else {
#pragma unroll
                for (int r = 0; r < 4; ++r)
                    Cout[(size_t)(row0 + r) * 512 + col] = acc[mi][ni][r] + bb;
            }
        }
    }
}

// ---------------- fused attention (R12 measured-best: attn ~70us) -----------
// Block = 512 thr = 8 waves, one (b,h); wave w owns 16 q-rows.
// K/V tiles dbuf in XOR-swizzled LDS (48KB). K-frag reads touch rows 4*fr+kf
// (stride-4 rows = bank-aliased), so K's swizzle is keyed on (row>>2)&7;
// V reads adjacent rows (nf*16+fr) -> keyed (row&7). T14 reg-staged dbuf.
// Fixed-max softmax: P = exp2(S + g2*A_phi). Q pre-scaled by SCALE*LOG2E.
__global__ __launch_bounds__(512, 3) void attn_kernel(
    const unsigned short* __restrict__ Qws,
    const unsigned short* __restrict__ Kws,
    const unsigned short* __restrict__ Vtws,
    const float* __restrict__ A_phi,
    const float* __restrict__ gamma_p,
    unsigned short* __restrict__ Oout)
{
    __shared__ __attribute__((aligned(16))) unsigned short Ks[2][64 * 64];
    __shared__ __attribute__((aligned(16))) unsigned short Vts[2][64 * 64];
    __shared__ __attribute__((aligned(16))) unsigned short Pl[8][16 * 64];

    int tid = threadIdx.x, lane = tid & 63, w = tid >> 6;
    int g = lane >> 4, fr = lane & 15;

    int id = blockIdx.x;                 // 0..511
    int b = (id & 7) >> 1, p = id & 1;
    int j = id >> 3;                     // 0..63
    int h = j & 7;
    int qt = ((j >> 3) << 1) | p;        // 0..15
    int bh = b * 8 + h;
    int q0 = qt * 128 + w * 16;          // wave's q base
    float g2 = gamma_p[0] * LOG2E;

    const unsigned short* Kb = Kws + (size_t)bh * NSEQ * 64;
    const unsigned short* Vb = Vtws + (size_t)bh * 64 * NSEQ;
    const float* Ap = A_phi + (size_t)b * NSEQ * NSEQ;

    short8v qf[2];
#pragma unroll
    for (int dc = 0; dc < 2; ++dc)
        qf[dc] = *(const short8v*)(Qws + ((size_t)bh * NSEQ + q0 + fr) * 64 + dc * 32 + g * 8);

    int c = tid;
    int krow = c >> 3;
    int kchunk = c & 7;
    int swK = (kchunk ^ ((krow >> 2) & 7)) * 8;
    int swV = (kchunk ^ (krow & 7)) * 8;
    int kcol = kchunk * 8;

    float l_lane[4] = {};
    f32x4 o_acc[4] = {};

    {
        short8v k0v = *(const short8v*)(Kb + c * 8);
        short8v v0v = *(const short8v*)(Vb + (size_t)krow * NSEQ + kcol);
        *(short8v*)(&Ks[0][krow * 64 + swK]) = k0v;
        *(short8v*)(&Vts[0][krow * 64 + swV]) = v0v;
    }
    __syncthreads();

    for (int kt = 0; kt < NSEQ / 64; ++kt) {
        int cur = kt & 1;

        short8v kreg, vreg;
        if (kt < NSEQ / 64 - 1) {
            kreg = *(const short8v*)(Kb + (kt + 1) * 4096 + c * 8);
            vreg = *(const short8v*)(Vb + (size_t)krow * NSEQ + (kt + 1) * 64 + kcol);
        }

        float4 av[4];
#pragma unroll
        for (int r = 0; r < 4; ++r)
            av[r] = *(const float4*)(Ap + (size_t)(q0 + g * 4 + r) * NSEQ + kt * 64 + 4 * fr);

        f32x4 sa[4] = {};
        __builtin_amdgcn_s_setprio(1);
#pragma unroll
        for (int kf = 0; kf < 4; ++kf) {
            int row = 4 * fr + kf;
#pragma unroll
            for (int dc = 0; dc < 2; ++dc) {
                short8v kfrag = *(const short8v*)(
                    &Ks[cur][row * 64 + (((dc * 4 + g) ^ ((row >> 2) & 7)) * 8)]);
                sa[kf] = __builtin_amdgcn_mfma_f32_16x16x32_bf16(qf[dc], kfrag, sa[kf], 0, 0, 0);
            }
        }
        __builtin_amdgcn_s_setprio(0);

#pragma unroll
        for (int r = 0; r < 4; ++r) {
            float e0 = exp2_fast(fmaf(g2, av[r].x, sa[0][r]));
            float e1 = exp2_fast(fmaf(g2, av[r].y, sa[1][r]));
            float e2 = exp2_fast(fmaf(g2, av[r].z, sa[2][r]));
            float e3 = exp2_fast(fmaf(g2, av[r].w, sa[3][r]));
            l_lane[r] += (e0 + e1) + (e2 + e3);
            int rp = g * 4 + r;
            uint2 pp;
            pp.x = pack_bf16_rh(e0, e1);
            pp.y = pack_bf16_rh(e2, e3);
            *(uint2*)(&Pl[w][rp * 64 + (((fr >> 1) ^ (rp & 7)) * 8) + (fr & 1) * 4]) = pp;
        }
        asm volatile("s_waitcnt lgkmcnt(0)" ::: "memory");

#pragma unroll
        for (int kc = 0; kc < 2; ++kc) {
            short8v pf = *(const short8v*)(
                &Pl[w][fr * 64 + (((kc * 4 + g) ^ (fr & 7)) * 8)]);
            __builtin_amdgcn_s_setprio(1);
#pragma unroll
            for (int nf = 0; nf < 4; ++nf) {
                int vrow = nf * 16 + fr;
                short8v vf = *(const short8v*)(
                    &Vts[cur][vrow * 64 + (((kc * 4 + g) ^ (vrow & 7)) * 8)]);
                o_acc[nf] = __builtin_amdgcn_mfma_f32_16x16x32_bf16(pf, vf, o_acc[nf], 0, 0, 0);
            }
            __builtin_amdgcn_s_setprio(0);
        }

        if (kt < NSEQ / 64 - 1) {
            *(short8v*)(&Ks[cur ^ 1][krow * 64 + swK]) = kreg;
            *(short8v*)(&Vts[cur ^ 1][krow * 64 + swV]) = vreg;
        }
        __syncthreads();
    }

#pragma unroll
    for (int r = 0; r < 4; ++r) {
        float l = l_lane[r];
        l += __shfl_xor(l, 1);
        l += __shfl_xor(l, 2);
        l += __shfl_xor(l, 4);
        l += __shfl_xor(l, 8);
        float inv = 1.0f / l;
        int qg = q0 + g * 4 + r;
#pragma unroll
        for (int nf = 0; nf < 4; ++nf)
            Oout[((size_t)b * NSEQ + qg) * 512 + h * 64 + nf * 16 + fr] =
                f2bf(o_acc[nf][r] * inv);
    }
}

extern "C" void kernel_launch(void* const* d_in, const int* in_sizes, int n_in,
                              void* d_out, int out_size, void* d_ws, size_t ws_size,
                              hipStream_t stream) {
    const float* x      = (const float*)d_in[0];
    const float* A_phi  = (const float*)d_in[1];
    const float* w_qkv  = (const float*)d_in[2];
    const float* b_qkv  = (const float*)d_in[3];
    const float* w_out  = (const float*)d_in[4];
    const float* b_out  = (const float*)d_in[5];
    const float* gamma  = (const float*)d_in[6];
    float* out = (float*)d_out;

    unsigned short* xb   = (unsigned short*)d_ws;
    unsigned short* wqb  = xb  + (size_t)8192 * 512;
    unsigned short* wob  = wqb + (size_t)1536 * 512;
    unsigned short* Qws  = wob + (size_t)512 * 512;
    unsigned short* Kws  = Qws + (size_t)4 * 8 * NSEQ * 64;
    unsigned short* Vtws = Kws + (size_t)4 * 8 * NSEQ * 64;
    unsigned short* Oat  = Vtws + (size_t)4 * 8 * NSEQ * 64;

    cvt_all<<<dim3(5120), dim3(256), 0, stream>>>(x, w_qkv, w_out, xb, wqb, wob);

    gemm_bf16<0, 128, 128, 12, 768><<<dim3(12, 64), dim3(256), 0, stream>>>(
        xb, wqb, b_qkv, Qws, Kws, Vtws, nullptr);

    attn_kernel<<<dim3(512), dim3(512), 0, stream>>>(
        Qws, Kws, Vtws, A_phi, gamma, Oat);

    gemm_bf16<1, 64, 128, 4, 512><<<dim3(4, 128), dim3(256), 0, stream>>>(
        Oat, wob, b_out, nullptr, nullptr, nullptr, out);
}